// Round 3
// baseline (2039.712 us; speedup 1.0000x reference)
//
#include <hip/hip_runtime.h>
#include <stdint.h>
#include <stddef.h>

// ---------------------------------------------------------------------------
// FedLite quantize: 8 independent KMeans (N=4096, d=1024, L=64, 10 iters)
// pts = x viewed as [R=8][N=4096][SUBD=1024] (reshape is layout-preserving).
// Init indices reproduce jax.random (threefry2x32, partitionable mode).
// ---------------------------------------------------------------------------

#define JAX_PARTITIONABLE 1

static constexpr int R_    = 8;
static constexpr int N_    = 4096;
static constexpr int L_    = 64;
static constexpr int D_    = 1024;   // SUBD
static constexpr int ITERS = 10;
static constexpr int ROWS  = R_ * N_;   // 32768 total sub-vectors
static constexpr int SEGS  = 8;         // n-segments for deterministic partial sums

// ---------------------------------------------------------------------------
// Threefry2x32 (JAX flavor): 20 rounds, rotations {13,15,26,6}/{17,29,16,24}
// ---------------------------------------------------------------------------
__device__ __forceinline__ unsigned rotl32(unsigned x, int r) {
  return (x << r) | (x >> (32 - r));
}

__device__ __forceinline__ void tf2x32(unsigned k0, unsigned k1,
                                       unsigned c0, unsigned c1,
                                       unsigned &o0, unsigned &o1) {
  unsigned ks2 = k0 ^ k1 ^ 0x1BD11BDAu;
  unsigned x0 = c0 + k0, x1 = c1 + k1;
#define TF_R4(a,b,c,d) { x0 += x1; x1 = rotl32(x1,a); x1 ^= x0; \
                         x0 += x1; x1 = rotl32(x1,b); x1 ^= x0; \
                         x0 += x1; x1 = rotl32(x1,c); x1 ^= x0; \
                         x0 += x1; x1 = rotl32(x1,d); x1 ^= x0; }
  TF_R4(13,15,26,6);  x0 += k1;  x1 += ks2 + 1u;
  TF_R4(17,29,16,24); x0 += ks2; x1 += k0  + 2u;
  TF_R4(13,15,26,6);  x0 += k0;  x1 += k1  + 3u;
  TF_R4(17,29,16,24); x0 += k1;  x1 += ks2 + 4u;
  TF_R4(13,15,26,6);  x0 += ks2; x1 += k0  + 5u;
#undef TF_R4
  o0 = x0; o1 = x1;
}

// split(key) -> (new_key, subkey), matching jax.random.split(key, 2)
__device__ __forceinline__ void jax_split2(unsigned k0, unsigned k1,
                                           unsigned &nk0, unsigned &nk1,
                                           unsigned &sk0, unsigned &sk1) {
#if JAX_PARTITIONABLE
  tf2x32(k0, k1, 0u, 0u, nk0, nk1);
  tf2x32(k0, k1, 0u, 1u, sk0, sk1);
#else
  unsigned a0, a1, b0, b1;
  tf2x32(k0, k1, 0u, 2u, a0, a1);
  tf2x32(k0, k1, 1u, 3u, b0, b1);
  nk0 = a0; nk1 = b0; sk0 = a1; sk1 = b1;
#endif
}

// ---------------------------------------------------------------------------
// Fused RNG + x2 kernel.
//  blocks [0, R_):        permutation init via 2 rounds of bitonic stable sort
//  blocks [R_, R_+2048):  x2[row] = ||pts[row]||^2, 16 rows per block.
// ---------------------------------------------------------------------------
__global__ __launch_bounds__(1024) void k_rng_x2(const float* __restrict__ pts,
                                                 float* __restrict__ x2,
                                                 int* __restrict__ init_idx) {
  __shared__ unsigned long long arr[N_];
  __shared__ unsigned short perm[N_];
  const int t = threadIdx.x;

  if (blockIdx.x >= R_) {
    // ---- x2 part: 16 rows per block, one wave per row ----
    const int row = (blockIdx.x - R_) * 16 + (t >> 6);
    const int lane = t & 63;
    const float4* P = (const float4*)(pts + (size_t)row * D_);
    float s = 0.f;
#pragma unroll
    for (int i = 0; i < 4; ++i) {
      float4 v = P[lane + 64 * i];
      s += v.x * v.x + v.y * v.y + v.z * v.z + v.w * v.w;
    }
#pragma unroll
    for (int m = 32; m > 0; m >>= 1) s += __shfl_down(s, m);
    if (lane == 0) x2[row] = s;
    return;
  }

  // ---- rng part ----
  const int r = blockIdx.x;

  unsigned k0, k1;
#if JAX_PARTITIONABLE
  tf2x32(0u, 42u, 0u, (unsigned)r, k0, k1);
#else
  {
    unsigned a0, a1, b0, b1;
    unsigned i0 = 2u * r, i1 = 2u * r + 1u;
    if (r < 4) { tf2x32(0u, 42u, i0, i0 + 8u, a0, a1); tf2x32(0u, 42u, i1, i1 + 8u, b0, b1); k0 = a0; k1 = b0; }
    else       { tf2x32(0u, 42u, i0 - 8u, i0, a0, a1); tf2x32(0u, 42u, i1 - 8u, i1, b0, b1); k0 = a1; k1 = b1; }
  }
#endif

  for (int i = t; i < N_; i += 1024) perm[i] = (unsigned short)i;
  __syncthreads();

  for (int round = 0; round < 2; ++round) {
    unsigned nk0, nk1, sk0, sk1;
    jax_split2(k0, k1, nk0, nk1, sk0, sk1);
    for (int j = t; j < N_; j += 1024) {
      unsigned o0, o1, skey;
#if JAX_PARTITIONABLE
      tf2x32(sk0, sk1, 0u, (unsigned)j, o0, o1);
      skey = o0 ^ o1;
#else
      if (j < 2048) { tf2x32(sk0, sk1, (unsigned)j, (unsigned)(j + 2048), o0, o1); skey = o0; }
      else          { tf2x32(sk0, sk1, (unsigned)(j - 2048), (unsigned)j, o0, o1); skey = o1; }
#endif
      arr[j] = ((unsigned long long)skey << 24) |
               ((unsigned long long)(unsigned)j << 12) |
               (unsigned long long)perm[j];
    }
    __syncthreads();
    for (int k = 2; k <= N_; k <<= 1) {
      for (int j2 = k >> 1; j2 >= 1; j2 >>= 1) {
        for (int q = t; q < N_ / 2; q += 1024) {
          int low = q & (j2 - 1);
          int i0 = ((q ^ low) << 1) | low;
          int i1 = i0 | j2;
          bool up = ((i0 & k) == 0);
          unsigned long long a = arr[i0], b = arr[i1];
          if ((a > b) == up) { arr[i0] = b; arr[i1] = a; }
        }
        __syncthreads();
      }
    }
    for (int j = t; j < N_; j += 1024) perm[j] = (unsigned short)(arr[j] & 0xFFFull);
    __syncthreads();
    k0 = nk0; k1 = nk1;
  }
  if (t < L_) init_idx[r * L_ + t] = (int)perm[t];
}

// ---------------------------------------------------------------------------
// Gather initial centers (+K-major copy) + c2; zero counts for iteration 0.
// One block per (r,l).
// ---------------------------------------------------------------------------
__global__ __launch_bounds__(256) void k_gather_init(const float* __restrict__ pts,
                                                     const int* __restrict__ init_idx,
                                                     float* __restrict__ centers,
                                                     float* __restrict__ centersT,
                                                     float* __restrict__ c2,
                                                     int* __restrict__ counts) {
  const int l = blockIdx.x, r = blockIdx.y, t = threadIdx.x;
  const int idx = init_idx[r * L_ + l];
  const float4* src = (const float4*)(pts + ((size_t)r * N_ + idx) * D_);
  float4* dst = (float4*)(centers + ((size_t)r * L_ + l) * D_);
  float4 v = src[t];
  dst[t] = v;
  // K-major copy: centersT[r][k][l]
  {
    const int k0 = t * 4;
    centersT[((size_t)r * D_ + k0 + 0) * L_ + l] = v.x;
    centersT[((size_t)r * D_ + k0 + 1) * L_ + l] = v.y;
    centersT[((size_t)r * D_ + k0 + 2) * L_ + l] = v.z;
    centersT[((size_t)r * D_ + k0 + 3) * L_ + l] = v.w;
  }
  float s = v.x * v.x + v.y * v.y + v.z * v.z + v.w * v.w;
  __shared__ float red[4];
  const int lane = t & 63, wave = t >> 6;
#pragma unroll
  for (int m = 32; m > 0; m >>= 1) s += __shfl_down(s, m);
  if (lane == 0) red[wave] = s;
  __syncthreads();
  if (t == 0) {
    c2[r * L_ + l] = red[0] + red[1] + red[2] + red[3];
    counts[r * L_ + l] = 0;
  }
}

// ---------------------------------------------------------------------------
// Assignment: labels[r][n] = argmin_l (x2[n] + c2[l]) - 2*dot(pts[n],centers[l])
// NEW STRUCTURE (LDS-read-bound fix):
//  - each WAVE owns 16 clusters; center values come from the K-major global
//    copy via wave-uniform SCALAR loads (SGPR operand of v_fmac) -> centers
//    never touch the LDS pipe.
//  - points: m=2 per lane, one ds_read_b64 per kk (LDS read traffic /6).
//  - point tile staged with XOR swizzle col ^ 4*((row>>2)&7): scalar
//    transposed writes become ~2-way (free), b64 reads stay aligned+balanced.
//  - fmaf chain per (point,cluster) stays sequential over kk with identical
//    operands -> d2 bit-identical to previous verified kernel.
// ---------------------------------------------------------------------------
#define BN 128
#define BK 64
__global__ __launch_bounds__(256, 1) void k_assign(const float* __restrict__ pts,
                                                   const float* __restrict__ centersT,
                                                   const float* __restrict__ c2g,
                                                   const float* __restrict__ x2g,
                                                   int* __restrict__ labels,
                                                   int* __restrict__ counts) {
  __shared__ __align__(16) float pT[2][BK][BN + 4];   // 67.6 KB
  __shared__ float smv[4][BN];
  __shared__ int   smi[4][BN];
  __shared__ int   hist[L_];
  const int t = threadIdx.x;
  const int r = blockIdx.y;
  const int n0 = blockIdx.x * BN;
  const int lane = t & 63;
  const int wv = __builtin_amdgcn_readfirstlane(t >> 6);   // wave id 0..3 (uniform)

  const float* Pr = pts + ((size_t)r * N_ + n0) * D_;
  const float* Cw = centersT + (size_t)r * D_ * L_ + wv * 16;  // wave's 16-cluster panel

  // staging coords: thread t loads float4 (4 k) of rows i*16+srow
  const int srow = t >> 4;        // 0..15
  const int q    = t & 15;        // 0..15
  const int skk  = q * 4;         // k-offset within tile, rows skk..skk+3
  const int swz  = 4 * (q & 7);   // write swizzle = 4*((row>>2)&7), row=skk+c

  if (t < L_) hist[t] = 0;

  float4 pv4[8];
  // prologue: stage K-tile 0
#pragma unroll
  for (int i = 0; i < 8; ++i)
    pv4[i] = *(const float4*)(Pr + (size_t)(i * 16 + srow) * D_ + skk);
#pragma unroll
  for (int i = 0; i < 8; ++i) {
    const int col = (i * 16 + srow) ^ swz;
    pT[0][skk + 0][col] = pv4[i].x;
    pT[0][skk + 1][col] = pv4[i].y;
    pT[0][skk + 2][col] = pv4[i].z;
    pT[0][skk + 3][col] = pv4[i].w;
  }
  __syncthreads();

  float acc[2][16];
#pragma unroll
  for (int ip = 0; ip < 2; ++ip)
#pragma unroll
    for (int j = 0; j < 16; ++j) acc[ip][j] = 0.f;

  constexpr int NKB = D_ / BK;   // 16
  for (int kb = 0; kb < NKB; ++kb) {
    const int cur = kb & 1;
    // prefetch next K-tile into registers (hides under compute)
    if (kb + 1 < NKB) {
      const int kbase = (kb + 1) * BK;
#pragma unroll
      for (int i = 0; i < 8; ++i)
        pv4[i] = *(const float4*)(Pr + (size_t)(i * 16 + srow) * D_ + kbase + skk);
    }

    const float* Ck = Cw + (size_t)kb * BK * L_;
#pragma unroll 4
    for (int kk = 0; kk < BK; ++kk) {
      // wave-uniform center slice -> scalar loads -> SGPR FMA operands
      const float* ck = Ck + kk * L_;
      float cv[16];
#pragma unroll
      for (int j = 0; j < 16; ++j) cv[j] = ck[j];
      const int colp = (2 * lane) ^ (4 * ((kk >> 2) & 7));
      const float2 pp = *(const float2*)&pT[cur][kk][colp];
#pragma unroll
      for (int j = 0; j < 16; ++j) {
        acc[0][j] = fmaf(pp.x, cv[j], acc[0][j]);
        acc[1][j] = fmaf(pp.y, cv[j], acc[1][j]);
      }
    }

    if (kb + 1 < NKB) {
      const int nxt = cur ^ 1;
#pragma unroll
      for (int i = 0; i < 8; ++i) {
        const int col = (i * 16 + srow) ^ swz;
        pT[nxt][skk + 0][col] = pv4[i].x;
        pT[nxt][skk + 1][col] = pv4[i].y;
        pT[nxt][skk + 2][col] = pv4[i].z;
        pT[nxt][skk + 3][col] = pv4[i].w;
      }
    }
    __syncthreads();
  }

  // epilogue: per-lane argmin over this wave's 16 clusters (first-min),
  // then cross-wave reduction in LDS (ascending wave = ascending cluster idx).
  float c2v[16];
#pragma unroll
  for (int j = 0; j < 16; ++j) c2v[j] = c2g[r * L_ + wv * 16 + j];

#pragma unroll
  for (int ip = 0; ip < 2; ++ip) {
    const int pl = lane * 2 + ip;
    const int n = n0 + pl;
    const float x2i = x2g[r * N_ + n];
    float bv = 3.4e38f;
    int bi = 0;
#pragma unroll
    for (int j = 0; j < 16; ++j) {
      float d2 = (x2i + c2v[j]) - 2.0f * acc[ip][j];
      if (d2 < bv) { bv = d2; bi = wv * 16 + j; }
    }
    smv[wv][pl] = bv;
    smi[wv][pl] = bi;
  }
  __syncthreads();
  if (t < BN) {
    float bv = smv[0][t];
    int bi = smi[0][t];
#pragma unroll
    for (int w = 1; w < 4; ++w) {
      float ov = smv[w][t];
      int oi = smi[w][t];
      if (ov < bv) { bv = ov; bi = oi; }   // ties keep lower wave = lower index
    }
    labels[r * N_ + n0 + t] = bi;
    atomicAdd(&hist[bi], 1);               // block-local histogram (deterministic)
  }
  __syncthreads();
  if (t < L_) atomicAdd(&counts[r * L_ + t], hist[t]);   // integer: bit-exact
}

// ---------------------------------------------------------------------------
// Partial per-cluster sums. Block = (dchunk, seg, r). 8-deep explicit load
// pipeline; adds stay strictly n-ascending -> bit-identical summation order.
// ---------------------------------------------------------------------------
__global__ __launch_bounds__(256) void k_update(const float* __restrict__ pts,
                                                const int* __restrict__ labels,
                                                float* __restrict__ psums) {
  __shared__ float acc[L_ * 256];
  __shared__ int lab[512];
  const int dch = blockIdx.x;   // 0..3
  const int seg = blockIdx.y;   // 0..7
  const int r   = blockIdx.z;   // 0..7
  const int t = threadIdx.x;

  for (int i = t; i < L_ * 256; i += 256) acc[i] = 0.f;
  for (int i = t; i < 512; i += 256) lab[i] = labels[r * N_ + seg * 512 + i];
  __syncthreads();

  const float* P = pts + ((size_t)r * N_ + seg * 512) * D_ + dch * 256 + t;
  float vbuf[8];
#pragma unroll
  for (int w = 0; w < 8; ++w) vbuf[w] = P[(size_t)w * D_];
  for (int nb = 0; nb < 504; nb += 8) {
#pragma unroll
    for (int w = 0; w < 8; ++w) {
      const int n = nb + w;
      const float cur = vbuf[w];
      vbuf[w] = P[(size_t)(n + 8) * D_];        // prefetch 8 ahead
      acc[lab[n] * 256 + t] += cur;             // in-order adds (bit-exact)
    }
  }
#pragma unroll
  for (int w = 0; w < 8; ++w) acc[lab[504 + w] * 256 + t] += vbuf[w];
  __syncthreads();

  float* S = psums + (((size_t)r * SEGS + seg) * L_) * D_ + dch * 256;
  for (int i = t; i < L_ * 256; i += 256) {
    int l = i >> 8, dd = i & 255;
    S[(size_t)l * D_ + dd] = acc[i];
  }
}

// ---------------------------------------------------------------------------
// Reduce partial sums -> new centers (both layouts) + c2. One block per (r,l).
// Re-zeroes counts for the next iteration's k_assign histogram.
// ---------------------------------------------------------------------------
__global__ __launch_bounds__(256) void k_reduce(const float* __restrict__ psums,
                                                int* __restrict__ counts,
                                                float* __restrict__ centers,
                                                float* __restrict__ centersT,
                                                float* __restrict__ c2) {
  const int l = blockIdx.x, r = blockIdx.y, t = threadIdx.x;
  const int cnt = counts[r * L_ + l];
  const float denom = fmaxf((float)cnt, 1.0f);

  float4 s = {0.f, 0.f, 0.f, 0.f};
#pragma unroll
  for (int seg = 0; seg < SEGS; ++seg) {
    const float4 v = *(const float4*)(psums + (((size_t)r * SEGS + seg) * L_ + l) * D_ + t * 4);
    s.x += v.x; s.y += v.y; s.z += v.z; s.w += v.w;
  }
  float4* Crow = (float4*)(centers + ((size_t)r * L_ + l) * D_);
  float4 cn;
  if (cnt > 0) {
    cn.x = s.x / denom; cn.y = s.y / denom; cn.z = s.z / denom; cn.w = s.w / denom;
  } else {
    cn = Crow[t];
  }
  Crow[t] = cn;
  {
    const int k0 = t * 4;
    centersT[((size_t)r * D_ + k0 + 0) * L_ + l] = cn.x;
    centersT[((size_t)r * D_ + k0 + 1) * L_ + l] = cn.y;
    centersT[((size_t)r * D_ + k0 + 2) * L_ + l] = cn.z;
    centersT[((size_t)r * D_ + k0 + 3) * L_ + l] = cn.w;
  }

  float ssq = cn.x * cn.x + cn.y * cn.y + cn.z * cn.z + cn.w * cn.w;
  __shared__ float red[4];
  const int lane = t & 63, wave = t >> 6;
#pragma unroll
  for (int m = 32; m > 0; m >>= 1) ssq += __shfl_down(ssq, m);
  if (lane == 0) red[wave] = ssq;
  __syncthreads();
  if (t == 0) {
    c2[r * L_ + l] = red[0] + red[1] + red[2] + red[3];
    counts[r * L_ + l] = 0;   // all threads read cnt before this barrier
  }
}

// ---------------------------------------------------------------------------
// Final gather: out[row] = centers[r][labels[row]] — 4 rows per block.
// ---------------------------------------------------------------------------
__global__ __launch_bounds__(256) void k_final(const float* __restrict__ centers,
                                               const int* __restrict__ labels,
                                               float* __restrict__ out) {
  const int t = threadIdx.x;
  const int row = blockIdx.x * 4 + (t >> 6);
  const int lane = t & 63;
  const int r = row >> 12;
  const int lab = labels[row];
  const float4* src = (const float4*)(centers + ((size_t)r * L_ + lab) * D_);
  float4* dst = (float4*)(out + (size_t)row * D_);
#pragma unroll
  for (int i = 0; i < 4; ++i) dst[lane + 64 * i] = src[lane + 64 * i];
}

// ---------------------------------------------------------------------------
extern "C" void kernel_launch(void* const* d_in, const int* in_sizes, int n_in,
                              void* d_out, int out_size, void* d_ws, size_t ws_size,
                              hipStream_t stream) {
  const float* x = (const float*)d_in[0];   // [512, 65536] == pts [8][4096][1024]
  float* out = (float*)d_out;               // [512, 65536] float32
  char* ws = (char*)d_ws;

  // workspace layout (bytes)
  float* centers  = (float*)(ws + 0);                        // 2 MB
  float* c2       = (float*)(ws + 2097152);                  // 2 KB
  float* x2       = (float*)(ws + 2099200);                  // 128 KB
  int*   labels   = (int*)  (ws + 2230272);                  // 128 KB
  int*   counts   = (int*)  (ws + 2361344);                  // 2 KB
  int*   initidx  = (int*)  (ws + 2363392);                  // 2 KB
  float* psums    = (float*)(ws + 2365440);                  // 16 MB
  float* centersT = (float*)(ws + 19142656);                 // 2 MB  [r][k][l]
  (void)in_sizes; (void)n_in; (void)out_size; (void)ws_size;

  // fused rng (8 blocks) + x2 (2048 blocks)
  k_rng_x2<<<dim3(R_ + ROWS / 16), 1024, 0, stream>>>(x, x2, initidx);
  k_gather_init<<<dim3(L_, R_), 256, 0, stream>>>(x, initidx, centers, centersT, c2, counts);

  for (int it = 0; it < ITERS; ++it) {
    k_assign<<<dim3(N_ / BN, R_), 256, 0, stream>>>(x, centersT, c2, x2, labels, counts);
    k_update<<<dim3(4, SEGS, R_), 256, 0, stream>>>(x, labels, psums);
    k_reduce<<<dim3(L_, R_), 256, 0, stream>>>(psums, counts, centers, centersT, c2);
  }
  k_assign<<<dim3(N_ / BN, R_), 256, 0, stream>>>(x, centersT, c2, x2, labels, counts);
  k_final<<<dim3(ROWS / 4), 256, 0, stream>>>(centers, labels, out);
}

// Round 4
// 1786.237 us; speedup vs baseline: 1.1419x; 1.1419x over previous
//
#include <hip/hip_runtime.h>
#include <stdint.h>
#include <stddef.h>

// ---------------------------------------------------------------------------
// FedLite quantize: 8 independent KMeans (N=4096, d=1024, L=64, 10 iters)
// pts = x viewed as [R=8][N=4096][SUBD=1024] (reshape is layout-preserving).
// Init indices reproduce jax.random (threefry2x32, partitionable mode).
// ---------------------------------------------------------------------------

#define JAX_PARTITIONABLE 1

static constexpr int R_    = 8;
static constexpr int N_    = 4096;
static constexpr int L_    = 64;
static constexpr int D_    = 1024;   // SUBD
static constexpr int ITERS = 10;
static constexpr int ROWS  = R_ * N_;   // 32768 total sub-vectors
static constexpr int SEGS  = 8;         // n-segments for deterministic partial sums

// ---------------------------------------------------------------------------
// Threefry2x32 (JAX flavor): 20 rounds, rotations {13,15,26,6}/{17,29,16,24}
// ---------------------------------------------------------------------------
__device__ __forceinline__ unsigned rotl32(unsigned x, int r) {
  return (x << r) | (x >> (32 - r));
}

__device__ __forceinline__ void tf2x32(unsigned k0, unsigned k1,
                                       unsigned c0, unsigned c1,
                                       unsigned &o0, unsigned &o1) {
  unsigned ks2 = k0 ^ k1 ^ 0x1BD11BDAu;
  unsigned x0 = c0 + k0, x1 = c1 + k1;
#define TF_R4(a,b,c,d) { x0 += x1; x1 = rotl32(x1,a); x1 ^= x0; \
                         x0 += x1; x1 = rotl32(x1,b); x1 ^= x0; \
                         x0 += x1; x1 = rotl32(x1,c); x1 ^= x0; \
                         x0 += x1; x1 = rotl32(x1,d); x1 ^= x0; }
  TF_R4(13,15,26,6);  x0 += k1;  x1 += ks2 + 1u;
  TF_R4(17,29,16,24); x0 += ks2; x1 += k0  + 2u;
  TF_R4(13,15,26,6);  x0 += k0;  x1 += k1  + 3u;
  TF_R4(17,29,16,24); x0 += k1;  x1 += ks2 + 4u;
  TF_R4(13,15,26,6);  x0 += ks2; x1 += k0  + 5u;
#undef TF_R4
  o0 = x0; o1 = x1;
}

// split(key) -> (new_key, subkey), matching jax.random.split(key, 2)
__device__ __forceinline__ void jax_split2(unsigned k0, unsigned k1,
                                           unsigned &nk0, unsigned &nk1,
                                           unsigned &sk0, unsigned &sk1) {
#if JAX_PARTITIONABLE
  tf2x32(k0, k1, 0u, 0u, nk0, nk1);
  tf2x32(k0, k1, 0u, 1u, sk0, sk1);
#else
  unsigned a0, a1, b0, b1;
  tf2x32(k0, k1, 0u, 2u, a0, a1);
  tf2x32(k0, k1, 1u, 3u, b0, b1);
  nk0 = a0; nk1 = b0; sk0 = a1; sk1 = b1;
#endif
}

// ---------------------------------------------------------------------------
// Fused RNG + x2 kernel.
//  blocks [0, R_):        permutation init via 2 rounds of bitonic stable sort
//  blocks [R_, R_+2048):  x2[row] = ||pts[row]||^2, 16 rows per block.
// ---------------------------------------------------------------------------
__global__ __launch_bounds__(1024) void k_rng_x2(const float* __restrict__ pts,
                                                 float* __restrict__ x2,
                                                 int* __restrict__ init_idx) {
  __shared__ unsigned long long arr[N_];
  __shared__ unsigned short perm[N_];
  const int t = threadIdx.x;

  if (blockIdx.x >= R_) {
    // ---- x2 part: 16 rows per block, one wave per row ----
    const int row = (blockIdx.x - R_) * 16 + (t >> 6);
    const int lane = t & 63;
    const float4* P = (const float4*)(pts + (size_t)row * D_);
    float s = 0.f;
#pragma unroll
    for (int i = 0; i < 4; ++i) {
      float4 v = P[lane + 64 * i];
      s += v.x * v.x + v.y * v.y + v.z * v.z + v.w * v.w;
    }
#pragma unroll
    for (int m = 32; m > 0; m >>= 1) s += __shfl_down(s, m);
    if (lane == 0) x2[row] = s;
    return;
  }

  // ---- rng part ----
  const int r = blockIdx.x;

  unsigned k0, k1;
#if JAX_PARTITIONABLE
  tf2x32(0u, 42u, 0u, (unsigned)r, k0, k1);
#else
  {
    unsigned a0, a1, b0, b1;
    unsigned i0 = 2u * r, i1 = 2u * r + 1u;
    if (r < 4) { tf2x32(0u, 42u, i0, i0 + 8u, a0, a1); tf2x32(0u, 42u, i1, i1 + 8u, b0, b1); k0 = a0; k1 = b0; }
    else       { tf2x32(0u, 42u, i0 - 8u, i0, a0, a1); tf2x32(0u, 42u, i1 - 8u, i1, b0, b1); k0 = a1; k1 = b1; }
  }
#endif

  for (int i = t; i < N_; i += 1024) perm[i] = (unsigned short)i;
  __syncthreads();

  for (int round = 0; round < 2; ++round) {
    unsigned nk0, nk1, sk0, sk1;
    jax_split2(k0, k1, nk0, nk1, sk0, sk1);
    for (int j = t; j < N_; j += 1024) {
      unsigned o0, o1, skey;
#if JAX_PARTITIONABLE
      tf2x32(sk0, sk1, 0u, (unsigned)j, o0, o1);
      skey = o0 ^ o1;
#else
      if (j < 2048) { tf2x32(sk0, sk1, (unsigned)j, (unsigned)(j + 2048), o0, o1); skey = o0; }
      else          { tf2x32(sk0, sk1, (unsigned)(j - 2048), (unsigned)j, o0, o1); skey = o1; }
#endif
      arr[j] = ((unsigned long long)skey << 24) |
               ((unsigned long long)(unsigned)j << 12) |
               (unsigned long long)perm[j];
    }
    __syncthreads();
    for (int k = 2; k <= N_; k <<= 1) {
      for (int j2 = k >> 1; j2 >= 1; j2 >>= 1) {
        for (int q = t; q < N_ / 2; q += 1024) {
          int low = q & (j2 - 1);
          int i0 = ((q ^ low) << 1) | low;
          int i1 = i0 | j2;
          bool up = ((i0 & k) == 0);
          unsigned long long a = arr[i0], b = arr[i1];
          if ((a > b) == up) { arr[i0] = b; arr[i1] = a; }
        }
        __syncthreads();
      }
    }
    for (int j = t; j < N_; j += 1024) perm[j] = (unsigned short)(arr[j] & 0xFFFull);
    __syncthreads();
    k0 = nk0; k1 = nk1;
  }
  if (t < L_) init_idx[r * L_ + t] = (int)perm[t];
}

// ---------------------------------------------------------------------------
// Gather initial centers + c2; zero counts for iteration 0. One block per (r,l).
// ---------------------------------------------------------------------------
__global__ __launch_bounds__(256) void k_gather_init(const float* __restrict__ pts,
                                                     const int* __restrict__ init_idx,
                                                     float* __restrict__ centers,
                                                     float* __restrict__ c2,
                                                     int* __restrict__ counts) {
  const int l = blockIdx.x, r = blockIdx.y, t = threadIdx.x;
  const int idx = init_idx[r * L_ + l];
  const float4* src = (const float4*)(pts + ((size_t)r * N_ + idx) * D_);
  float4* dst = (float4*)(centers + ((size_t)r * L_ + l) * D_);
  float4 v = src[t];
  dst[t] = v;
  float s = v.x * v.x + v.y * v.y + v.z * v.z + v.w * v.w;
  __shared__ float red[4];
  const int lane = t & 63, wave = t >> 6;
#pragma unroll
  for (int m = 32; m > 0; m >>= 1) s += __shfl_down(s, m);
  if (lane == 0) red[wave] = s;
  __syncthreads();
  if (t == 0) {
    c2[r * L_ + l] = red[0] + red[1] + red[2] + red[3];
    counts[r * L_ + l] = 0;
  }
}

// ---------------------------------------------------------------------------
// Assignment: labels[r][n] = argmin_l (x2[n] + c2[l]) - 2*dot(pts[n],centers[l])
// DPP-QUAD STRUCTURE (cuts LDS read traffic ~25% and moves the c-operand
// broadcast to the VALU pipe):
//  - register tile per lane: m=8 points x n=4 clusters (l0 = (lane>>2)*4).
//  - lane holds c[kk][lane] (b128 per 4 kk from K-contiguous cL[l][kk] tile);
//    the 4 needed c-values per kk come from v_mov_dpp quad_perm broadcasts
//    (VALU pipe, no LDS).
//  - p tile transposed [kk][p] with XOR write/read swizzle (verified round 3:
//    conflicts 1.1e7 -> 1e6); p-values read as 2x ds_read_b128 per kk.
//  - fmaf chain per (point,cluster) strictly kk-ascending with identical
//    operands -> d2 bit-identical to the verified kernels -> labels identical.
//  - per-cluster counts folded in (LDS hist + integer atomics, bit-exact).
// ---------------------------------------------------------------------------
#define BN 128
#define BK 64
__global__ __launch_bounds__(256, 1) void k_assign(const float* __restrict__ pts,
                                                   const float* __restrict__ centers,
                                                   const float* __restrict__ c2g,
                                                   const float* __restrict__ x2g,
                                                   int* __restrict__ labels,
                                                   int* __restrict__ counts) {
  __shared__ __align__(16) float pT[2][BK][BN + 4];   // [buf][kk][p^swz], 67.6 KB
  __shared__ __align__(16) float cL[2][L_][BK + 4];   // [buf][l][kk],     34.8 KB
  __shared__ int hist[L_];
  const int t = threadIdx.x;
  const int r = blockIdx.y;
  const int n0 = blockIdx.x * BN;
  const int lane = t & 63;
  const int w  = t >> 6;            // wave 0..3
  const int u  = lane & 3;          // point-group within wave
  const int qq = lane >> 2;         // cluster quad 0..15
  const int p0 = (w * 4 + u) * 8;   // this lane's 8 points p0..p0+7
  const int l0 = qq * 4;            // this lane's 4 clusters l0..l0+3

  const float* Pr = pts + ((size_t)r * N_ + n0) * D_;
  const float* Cr = centers + (size_t)r * L_ * D_;

  // p staging (round-3 verified): thread t loads rows i*16+srow, k skk..skk+3,
  // writes transposed with column XOR swizzle sigma(kk) = (kk>>2)&7.
  const int srow = t >> 4;          // 0..15
  const int skk  = (t & 15) * 4;    // 0..60
  const int swz  = 4 * (t & 7);     // = 4*(((skk+c)>>2)&7) for c=0..3
  // c staging: thread t covers cluster row t>>2, k seg*16..seg*16+15
  const int crow = t >> 2;          // 0..63
  const int cseg = (t & 3) * 16;    // 0,16,32,48

  if (t < L_) hist[t] = 0;

  float4 pv4[8], cv4[4];

  // prologue: stage K-tile 0
#pragma unroll
  for (int i = 0; i < 8; ++i)
    pv4[i] = *(const float4*)(Pr + (size_t)(i * 16 + srow) * D_ + skk);
#pragma unroll
  for (int c = 0; c < 4; ++c)
    cv4[c] = *(const float4*)(Cr + (size_t)crow * D_ + cseg + 4 * c);
#pragma unroll
  for (int i = 0; i < 8; ++i) {
    const int col = (i * 16 + srow) ^ swz;
    pT[0][skk + 0][col] = pv4[i].x;
    pT[0][skk + 1][col] = pv4[i].y;
    pT[0][skk + 2][col] = pv4[i].z;
    pT[0][skk + 3][col] = pv4[i].w;
  }
#pragma unroll
  for (int c = 0; c < 4; ++c)
    *(float4*)&cL[0][crow][cseg + 4 * c] = cv4[c];
  __syncthreads();

  float acc[8][4];
#pragma unroll
  for (int i = 0; i < 8; ++i)
#pragma unroll
    for (int j = 0; j < 4; ++j) acc[i][j] = 0.f;

  constexpr int NKB = D_ / BK;   // 16
  for (int kb = 0; kb < NKB; ++kb) {
    const int cur = kb & 1;
    // prefetch next K-tile into registers (hides under compute)
    if (kb + 1 < NKB) {
      const int kbase = (kb + 1) * BK;
#pragma unroll
      for (int i = 0; i < 8; ++i)
        pv4[i] = *(const float4*)(Pr + (size_t)(i * 16 + srow) * D_ + kbase + skk);
#pragma unroll
      for (int c = 0; c < 4; ++c)
        cv4[c] = *(const float4*)(Cr + (size_t)crow * D_ + kbase + cseg + 4 * c);
    }

#pragma unroll 4
    for (int kk4 = 0; kk4 < 16; ++kk4) {
      const int sig4 = 4 * (kk4 & 7);
      const int colA = p0 ^ sig4;             // 16B-aligned (p0%8==0, sig4%4==0)
      const float4 cq = *(const float4*)&cL[cur][lane][kk4 * 4];
      const float ca[4] = {cq.x, cq.y, cq.z, cq.w};
#pragma unroll
      for (int e = 0; e < 4; ++e) {
        const int kk = kk4 * 4 + e;
        const float4 A = *(const float4*)&pT[cur][kk][colA];       // pts p0..p0+3
        const float4 B = *(const float4*)&pT[cur][kk][colA ^ 4];   // pts p0+4..p0+7
        const int ci = __float_as_int(ca[e]);
        // quad_perm[j,j,j,j] broadcasts lane (quad_base+j) -> c[kk][l0+j]
        const float cb0 = __int_as_float(__builtin_amdgcn_mov_dpp(ci, 0x00, 0xF, 0xF, true));
        const float cb1 = __int_as_float(__builtin_amdgcn_mov_dpp(ci, 0x55, 0xF, 0xF, true));
        const float cb2 = __int_as_float(__builtin_amdgcn_mov_dpp(ci, 0xAA, 0xF, 0xF, true));
        const float cb3 = __int_as_float(__builtin_amdgcn_mov_dpp(ci, 0xFF, 0xF, 0xF, true));
        const float pv[8] = {A.x, A.y, A.z, A.w, B.x, B.y, B.z, B.w};
#pragma unroll
        for (int i = 0; i < 8; ++i) {
          acc[i][0] = fmaf(pv[i], cb0, acc[i][0]);
          acc[i][1] = fmaf(pv[i], cb1, acc[i][1]);
          acc[i][2] = fmaf(pv[i], cb2, acc[i][2]);
          acc[i][3] = fmaf(pv[i], cb3, acc[i][3]);
        }
      }
    }

    // write the prefetched tile into the other buffer
    if (kb + 1 < NKB) {
      const int nxt = cur ^ 1;
#pragma unroll
      for (int i = 0; i < 8; ++i) {
        const int col = (i * 16 + srow) ^ swz;
        pT[nxt][skk + 0][col] = pv4[i].x;
        pT[nxt][skk + 1][col] = pv4[i].y;
        pT[nxt][skk + 2][col] = pv4[i].z;
        pT[nxt][skk + 3][col] = pv4[i].w;
      }
#pragma unroll
      for (int c = 0; c < 4; ++c)
        *(float4*)&cL[nxt][crow][cseg + 4 * c] = cv4[c];
    }
    __syncthreads();
  }

  // epilogue: per-lane first-min over its 4 clusters, then exact first-min
  // across the 16 quads sharing each point via (value,index) shuffle reduce.
  float c2v[4];
#pragma unroll
  for (int j = 0; j < 4; ++j) c2v[j] = c2g[r * L_ + l0 + j];

#pragma unroll
  for (int i = 0; i < 8; ++i) {
    const int n = n0 + p0 + i;
    const float x2i = x2g[r * N_ + n];
    float bv = 3.4e38f;
    int bi = 0;
#pragma unroll
    for (int j = 0; j < 4; ++j) {
      float d2 = (x2i + c2v[j]) - 2.0f * acc[i][j];
      if (d2 < bv) { bv = d2; bi = l0 + j; }
    }
#pragma unroll
    for (int m = 4; m <= 32; m <<= 1) {
      float ov = __shfl_xor(bv, m);
      int oi = __shfl_xor(bi, m);
      if (ov < bv || (ov == bv && oi < bi)) { bv = ov; bi = oi; }
    }
    if (qq == 0) {
      labels[r * N_ + n] = bi;
      atomicAdd(&hist[bi], 1);             // block-local histogram (deterministic)
    }
  }
  __syncthreads();
  if (t < L_) atomicAdd(&counts[r * L_ + t], hist[t]);   // integer: bit-exact
}

// ---------------------------------------------------------------------------
// Partial per-cluster sums. Block = (dchunk, seg, r). 8-deep explicit load
// pipeline; adds stay strictly n-ascending -> bit-identical summation order.
// ---------------------------------------------------------------------------
__global__ __launch_bounds__(256) void k_update(const float* __restrict__ pts,
                                                const int* __restrict__ labels,
                                                float* __restrict__ psums) {
  __shared__ float acc[L_ * 256];
  __shared__ int lab[512];
  const int dch = blockIdx.x;   // 0..3
  const int seg = blockIdx.y;   // 0..7
  const int r   = blockIdx.z;   // 0..7
  const int t = threadIdx.x;

  for (int i = t; i < L_ * 256; i += 256) acc[i] = 0.f;
  for (int i = t; i < 512; i += 256) lab[i] = labels[r * N_ + seg * 512 + i];
  __syncthreads();

  const float* P = pts + ((size_t)r * N_ + seg * 512) * D_ + dch * 256 + t;
  float vbuf[8];
#pragma unroll
  for (int w = 0; w < 8; ++w) vbuf[w] = P[(size_t)w * D_];
  for (int nb = 0; nb < 504; nb += 8) {
#pragma unroll
    for (int w = 0; w < 8; ++w) {
      const int n = nb + w;
      const float cur = vbuf[w];
      vbuf[w] = P[(size_t)(n + 8) * D_];        // prefetch 8 ahead
      acc[lab[n] * 256 + t] += cur;             // in-order adds (bit-exact)
    }
  }
#pragma unroll
  for (int w = 0; w < 8; ++w) acc[lab[504 + w] * 256 + t] += vbuf[w];
  __syncthreads();

  float* S = psums + (((size_t)r * SEGS + seg) * L_) * D_ + dch * 256;
  for (int i = t; i < L_ * 256; i += 256) {
    int l = i >> 8, dd = i & 255;
    S[(size_t)l * D_ + dd] = acc[i];
  }
}

// ---------------------------------------------------------------------------
// Reduce partial sums -> new centers + c2. One block per (r,l).
// Re-zeroes counts for the next iteration's k_assign histogram.
// ---------------------------------------------------------------------------
__global__ __launch_bounds__(256) void k_reduce(const float* __restrict__ psums,
                                                int* __restrict__ counts,
                                                float* __restrict__ centers,
                                                float* __restrict__ c2) {
  const int l = blockIdx.x, r = blockIdx.y, t = threadIdx.x;
  const int cnt = counts[r * L_ + l];
  const float denom = fmaxf((float)cnt, 1.0f);

  float4 s = {0.f, 0.f, 0.f, 0.f};
#pragma unroll
  for (int seg = 0; seg < SEGS; ++seg) {
    const float4 v = *(const float4*)(psums + (((size_t)r * SEGS + seg) * L_ + l) * D_ + t * 4);
    s.x += v.x; s.y += v.y; s.z += v.z; s.w += v.w;
  }
  float4* Crow = (float4*)(centers + ((size_t)r * L_ + l) * D_);
  float4 cn;
  if (cnt > 0) {
    cn.x = s.x / denom; cn.y = s.y / denom; cn.z = s.z / denom; cn.w = s.w / denom;
  } else {
    cn = Crow[t];
  }
  Crow[t] = cn;

  float ssq = cn.x * cn.x + cn.y * cn.y + cn.z * cn.z + cn.w * cn.w;
  __shared__ float red[4];
  const int lane = t & 63, wave = t >> 6;
#pragma unroll
  for (int m = 32; m > 0; m >>= 1) ssq += __shfl_down(ssq, m);
  if (lane == 0) red[wave] = ssq;
  __syncthreads();
  if (t == 0) {
    c2[r * L_ + l] = red[0] + red[1] + red[2] + red[3];
    counts[r * L_ + l] = 0;   // all threads read cnt before this barrier
  }
}

// ---------------------------------------------------------------------------
// Final gather: out[row] = centers[r][labels[row]] — 4 rows per block.
// ---------------------------------------------------------------------------
__global__ __launch_bounds__(256) void k_final(const float* __restrict__ centers,
                                               const int* __restrict__ labels,
                                               float* __restrict__ out) {
  const int t = threadIdx.x;
  const int row = blockIdx.x * 4 + (t >> 6);
  const int lane = t & 63;
  const int r = row >> 12;
  const int lab = labels[row];
  const float4* src = (const float4*)(centers + ((size_t)r * L_ + lab) * D_);
  float4* dst = (float4*)(out + (size_t)row * D_);
#pragma unroll
  for (int i = 0; i < 4; ++i) dst[lane + 64 * i] = src[lane + 64 * i];
}

// ---------------------------------------------------------------------------
extern "C" void kernel_launch(void* const* d_in, const int* in_sizes, int n_in,
                              void* d_out, int out_size, void* d_ws, size_t ws_size,
                              hipStream_t stream) {
  const float* x = (const float*)d_in[0];   // [512, 65536] == pts [8][4096][1024]
  float* out = (float*)d_out;               // [512, 65536] float32
  char* ws = (char*)d_ws;

  // workspace layout (bytes)
  float* centers = (float*)(ws + 0);                        // 2 MB
  float* c2      = (float*)(ws + 2097152);                  // 2 KB
  float* x2      = (float*)(ws + 2099200);                  // 128 KB
  int*   labels  = (int*)  (ws + 2230272);                  // 128 KB
  int*   counts  = (int*)  (ws + 2361344);                  // 2 KB
  int*   initidx = (int*)  (ws + 2363392);                  // 2 KB
  float* psums   = (float*)(ws + 2365440);                  // 16 MB
  (void)in_sizes; (void)n_in; (void)out_size; (void)ws_size;

  // fused rng (8 blocks) + x2 (2048 blocks)
  k_rng_x2<<<dim3(R_ + ROWS / 16), 1024, 0, stream>>>(x, x2, initidx);
  k_gather_init<<<dim3(L_, R_), 256, 0, stream>>>(x, initidx, centers, c2, counts);

  for (int it = 0; it < ITERS; ++it) {
    k_assign<<<dim3(N_ / BN, R_), 256, 0, stream>>>(x, centers, c2, x2, labels, counts);
    k_update<<<dim3(4, SEGS, R_), 256, 0, stream>>>(x, labels, psums);
    k_reduce<<<dim3(L_, R_), 256, 0, stream>>>(psums, counts, centers, c2);
  }
  k_assign<<<dim3(N_ / BN, R_), 256, 0, stream>>>(x, centers, c2, x2, labels, counts);
  k_final<<<dim3(ROWS / 4), 256, 0, stream>>>(centers, labels, out);
}

// Round 6
// 1536.304 us; speedup vs baseline: 1.3277x; 1.1627x over previous
//
#include <hip/hip_runtime.h>
#include <stdint.h>
#include <stddef.h>

// ---------------------------------------------------------------------------
// FedLite quantize: 8 independent KMeans (N=4096, d=1024, L=64, 10 iters)
// pts = x viewed as [R=8][N=4096][SUBD=1024] (reshape is layout-preserving).
// Init indices reproduce jax.random (threefry2x32, partitionable mode).
// ---------------------------------------------------------------------------

#define JAX_PARTITIONABLE 1

static constexpr int R_    = 8;
static constexpr int N_    = 4096;
static constexpr int L_    = 64;
static constexpr int D_    = 1024;   // SUBD
static constexpr int ITERS = 10;
static constexpr int ROWS  = R_ * N_;   // 32768 total sub-vectors
static constexpr int SEGS  = 8;         // n-segments for deterministic partial sums

// ---------------------------------------------------------------------------
// Threefry2x32 (JAX flavor): 20 rounds, rotations {13,15,26,6}/{17,29,16,24}
// ---------------------------------------------------------------------------
__device__ __forceinline__ unsigned rotl32(unsigned x, int r) {
  return (x << r) | (x >> (32 - r));
}

__device__ __forceinline__ void tf2x32(unsigned k0, unsigned k1,
                                       unsigned c0, unsigned c1,
                                       unsigned &o0, unsigned &o1) {
  unsigned ks2 = k0 ^ k1 ^ 0x1BD11BDAu;
  unsigned x0 = c0 + k0, x1 = c1 + k1;
#define TF_R4(a,b,c,d) { x0 += x1; x1 = rotl32(x1,a); x1 ^= x0; \
                         x0 += x1; x1 = rotl32(x1,b); x1 ^= x0; \
                         x0 += x1; x1 = rotl32(x1,c); x1 ^= x0; \
                         x0 += x1; x1 = rotl32(x1,d); x1 ^= x0; }
  TF_R4(13,15,26,6);  x0 += k1;  x1 += ks2 + 1u;
  TF_R4(17,29,16,24); x0 += ks2; x1 += k0  + 2u;
  TF_R4(13,15,26,6);  x0 += k0;  x1 += k1  + 3u;
  TF_R4(17,29,16,24); x0 += k1;  x1 += ks2 + 4u;
  TF_R4(13,15,26,6);  x0 += ks2; x1 += k0  + 5u;
#undef TF_R4
  o0 = x0; o1 = x1;
}

// split(key) -> (new_key, subkey), matching jax.random.split(key, 2)
__device__ __forceinline__ void jax_split2(unsigned k0, unsigned k1,
                                           unsigned &nk0, unsigned &nk1,
                                           unsigned &sk0, unsigned &sk1) {
#if JAX_PARTITIONABLE
  tf2x32(k0, k1, 0u, 0u, nk0, nk1);
  tf2x32(k0, k1, 0u, 1u, sk0, sk1);
#else
  unsigned a0, a1, b0, b1;
  tf2x32(k0, k1, 0u, 2u, a0, a1);
  tf2x32(k0, k1, 1u, 3u, b0, b1);
  nk0 = a0; nk1 = b0; sk0 = a1; sk1 = b1;
#endif
}

// ---------------------------------------------------------------------------
// Fused RNG + x2 kernel.
//  blocks [0, R_):        permutation init via 2 rounds of bitonic stable sort
//  blocks [R_, R_+2048):  x2[row] = ||pts[row]||^2, 16 rows per block.
// ---------------------------------------------------------------------------
__global__ __launch_bounds__(1024) void k_rng_x2(const float* __restrict__ pts,
                                                 float* __restrict__ x2,
                                                 int* __restrict__ init_idx) {
  __shared__ unsigned long long arr[N_];
  __shared__ unsigned short perm[N_];
  const int t = threadIdx.x;

  if (blockIdx.x >= R_) {
    // ---- x2 part: 16 rows per block, one wave per row ----
    const int row = (blockIdx.x - R_) * 16 + (t >> 6);
    const int lane = t & 63;
    const float4* P = (const float4*)(pts + (size_t)row * D_);
    float s = 0.f;
#pragma unroll
    for (int i = 0; i < 4; ++i) {
      float4 v = P[lane + 64 * i];
      s += v.x * v.x + v.y * v.y + v.z * v.z + v.w * v.w;
    }
#pragma unroll
    for (int m = 32; m > 0; m >>= 1) s += __shfl_down(s, m);
    if (lane == 0) x2[row] = s;
    return;
  }

  // ---- rng part ----
  const int r = blockIdx.x;

  unsigned k0, k1;
#if JAX_PARTITIONABLE
  tf2x32(0u, 42u, 0u, (unsigned)r, k0, k1);
#else
  {
    unsigned a0, a1, b0, b1;
    unsigned i0 = 2u * r, i1 = 2u * r + 1u;
    if (r < 4) { tf2x32(0u, 42u, i0, i0 + 8u, a0, a1); tf2x32(0u, 42u, i1, i1 + 8u, b0, b1); k0 = a0; k1 = b0; }
    else       { tf2x32(0u, 42u, i0 - 8u, i0, a0, a1); tf2x32(0u, 42u, i1 - 8u, i1, b0, b1); k0 = a1; k1 = b1; }
  }
#endif

  for (int i = t; i < N_; i += 1024) perm[i] = (unsigned short)i;
  __syncthreads();

  for (int round = 0; round < 2; ++round) {
    unsigned nk0, nk1, sk0, sk1;
    jax_split2(k0, k1, nk0, nk1, sk0, sk1);
    for (int j = t; j < N_; j += 1024) {
      unsigned o0, o1, skey;
#if JAX_PARTITIONABLE
      tf2x32(sk0, sk1, 0u, (unsigned)j, o0, o1);
      skey = o0 ^ o1;
#else
      if (j < 2048) { tf2x32(sk0, sk1, (unsigned)j, (unsigned)(j + 2048), o0, o1); skey = o0; }
      else          { tf2x32(sk0, sk1, (unsigned)(j - 2048), (unsigned)j, o0, o1); skey = o1; }
#endif
      arr[j] = ((unsigned long long)skey << 24) |
               ((unsigned long long)(unsigned)j << 12) |
               (unsigned long long)perm[j];
    }
    __syncthreads();
    for (int k = 2; k <= N_; k <<= 1) {
      for (int j2 = k >> 1; j2 >= 1; j2 >>= 1) {
        for (int q = t; q < N_ / 2; q += 1024) {
          int low = q & (j2 - 1);
          int i0 = ((q ^ low) << 1) | low;
          int i1 = i0 | j2;
          bool up = ((i0 & k) == 0);
          unsigned long long a = arr[i0], b = arr[i1];
          if ((a > b) == up) { arr[i0] = b; arr[i1] = a; }
        }
        __syncthreads();
      }
    }
    for (int j = t; j < N_; j += 1024) perm[j] = (unsigned short)(arr[j] & 0xFFFull);
    __syncthreads();
    k0 = nk0; k1 = nk1;
  }
  if (t < L_) init_idx[r * L_ + t] = (int)perm[t];
}

// ---------------------------------------------------------------------------
// Gather initial centers + c2; zero counts for iteration 0. One block per (r,l).
// ---------------------------------------------------------------------------
__global__ __launch_bounds__(256) void k_gather_init(const float* __restrict__ pts,
                                                     const int* __restrict__ init_idx,
                                                     float* __restrict__ centers,
                                                     float* __restrict__ c2,
                                                     int* __restrict__ counts) {
  const int l = blockIdx.x, r = blockIdx.y, t = threadIdx.x;
  const int idx = init_idx[r * L_ + l];
  const float4* src = (const float4*)(pts + ((size_t)r * N_ + idx) * D_);
  float4* dst = (float4*)(centers + ((size_t)r * L_ + l) * D_);
  float4 v = src[t];
  dst[t] = v;
  float s = v.x * v.x + v.y * v.y + v.z * v.z + v.w * v.w;
  __shared__ float red[4];
  const int lane = t & 63, wave = t >> 6;
#pragma unroll
  for (int m = 32; m > 0; m >>= 1) s += __shfl_down(s, m);
  if (lane == 0) red[wave] = s;
  __syncthreads();
  if (t == 0) {
    c2[r * L_ + l] = red[0] + red[1] + red[2] + red[3];
    counts[r * L_ + l] = 0;
  }
}

// ---------------------------------------------------------------------------
// Assignment: labels[r][n] = argmin_l (x2[n] + c2[l]) - 2*dot(pts[n],centers[l])
// OCCUPANCY FIX: BN=64 tile, 68 KB LDS -> 2 blocks/CU (grid 512), 2 waves/SIMD.
// Keeps the verified DPP-quad structure:
//  - per-lane tile m=4 pts x n=4 clusters; lane holds c[lane][kk] (b128 per
//    4 kk); the 4 c-values per kk come from v_mov_dpp quad_perm broadcasts.
//  - p tile transposed [kk][p] with XOR swizzle (verified: conflicts /3).
//  - fmaf chain per (point,cluster) strictly kk-ascending with identical
//    operands -> d2 bit-identical to the verified kernels -> labels identical.
//  - per-cluster counts folded in (LDS hist + integer atomics, bit-exact).
// ---------------------------------------------------------------------------
#define BN 64
#define BK 64
__global__ __launch_bounds__(256, 2) void k_assign(const float* __restrict__ pts,
                                                   const float* __restrict__ centers,
                                                   const float* __restrict__ c2g,
                                                   const float* __restrict__ x2g,
                                                   int* __restrict__ labels,
                                                   int* __restrict__ counts) {
  __shared__ __align__(16) float pT[2][BK][BN + 4];   // [buf][kk][p^swz], 34.8 KB
  __shared__ __align__(16) float cL[2][L_][BK + 4];   // [buf][l][kk],     34.8 KB
  __shared__ int hist[L_];
  const int t = threadIdx.x;
  const int r = blockIdx.y;
  const int n0 = blockIdx.x * BN;
  const int lane = t & 63;
  const int w  = t >> 6;            // wave 0..3
  const int u  = lane & 3;          // point-group within wave
  const int qq = lane >> 2;         // cluster quad 0..15
  const int p0 = w * 16 + u * 4;    // this lane's 4 points p0..p0+3
  const int l0 = qq * 4;            // this lane's 4 clusters l0..l0+3

  const float* Pr = pts + ((size_t)r * N_ + n0) * D_;
  const float* Cr = centers + (size_t)r * L_ * D_;

  // staging: thread t loads float4 (4 k) of rows i*16+srow, k skk..skk+3,
  // for BOTH the 64-pt tile and the 64-cluster tile (same geometry).
  const int srow = t >> 4;          // 0..15
  const int skk  = (t & 15) * 4;    // 0..60
  const int swz  = 4 * (t & 7);     // = 4*(((skk+c)>>2)&7) for c=0..3

  if (t < L_) hist[t] = 0;

  float4 pv4[4], cv4[4];

  // prologue: stage K-tile 0
#pragma unroll
  for (int i = 0; i < 4; ++i) {
    pv4[i] = *(const float4*)(Pr + (size_t)(i * 16 + srow) * D_ + skk);
    cv4[i] = *(const float4*)(Cr + (size_t)(i * 16 + srow) * D_ + skk);
  }
#pragma unroll
  for (int i = 0; i < 4; ++i) {
    const int row = i * 16 + srow;
    const int col = row ^ swz;
    pT[0][skk + 0][col] = pv4[i].x;
    pT[0][skk + 1][col] = pv4[i].y;
    pT[0][skk + 2][col] = pv4[i].z;
    pT[0][skk + 3][col] = pv4[i].w;
    *(float4*)&cL[0][row][skk] = cv4[i];
  }
  __syncthreads();

  float acc[4][4];
#pragma unroll
  for (int i = 0; i < 4; ++i)
#pragma unroll
    for (int j = 0; j < 4; ++j) acc[i][j] = 0.f;

  constexpr int NKB = D_ / BK;   // 16
  for (int kb = 0; kb < NKB; ++kb) {
    const int cur = kb & 1;
    // prefetch next K-tile into registers (hides under compute)
    if (kb + 1 < NKB) {
      const int kbase = (kb + 1) * BK;
#pragma unroll
      for (int i = 0; i < 4; ++i) {
        pv4[i] = *(const float4*)(Pr + (size_t)(i * 16 + srow) * D_ + kbase + skk);
        cv4[i] = *(const float4*)(Cr + (size_t)(i * 16 + srow) * D_ + kbase + skk);
      }
    }

#pragma unroll 4
    for (int kk4 = 0; kk4 < 16; ++kk4) {
      const int sig4 = 4 * (kk4 & 7);
      const int colA = p0 ^ sig4;             // 16B-aligned
      const float4 cq = *(const float4*)&cL[cur][lane][kk4 * 4];
      const float ca[4] = {cq.x, cq.y, cq.z, cq.w};
#pragma unroll
      for (int e = 0; e < 4; ++e) {
        const int kk = kk4 * 4 + e;
        const float4 A = *(const float4*)&pT[cur][kk][colA];   // pts p0..p0+3
        const int ci = __float_as_int(ca[e]);
        // quad_perm[j,j,j,j] broadcasts lane (quad_base+j) -> c[kk][l0+j]
        const float cb0 = __int_as_float(__builtin_amdgcn_mov_dpp(ci, 0x00, 0xF, 0xF, true));
        const float cb1 = __int_as_float(__builtin_amdgcn_mov_dpp(ci, 0x55, 0xF, 0xF, true));
        const float cb2 = __int_as_float(__builtin_amdgcn_mov_dpp(ci, 0xAA, 0xF, 0xF, true));
        const float cb3 = __int_as_float(__builtin_amdgcn_mov_dpp(ci, 0xFF, 0xF, 0xF, true));
        const float pv[4] = {A.x, A.y, A.z, A.w};
#pragma unroll
        for (int i = 0; i < 4; ++i) {
          acc[i][0] = fmaf(pv[i], cb0, acc[i][0]);
          acc[i][1] = fmaf(pv[i], cb1, acc[i][1]);
          acc[i][2] = fmaf(pv[i], cb2, acc[i][2]);
          acc[i][3] = fmaf(pv[i], cb3, acc[i][3]);
        }
      }
    }

    // write the prefetched tile into the other buffer
    if (kb + 1 < NKB) {
      const int nxt = cur ^ 1;
#pragma unroll
      for (int i = 0; i < 4; ++i) {
        const int row = i * 16 + srow;
        const int col = row ^ swz;
        pT[nxt][skk + 0][col] = pv4[i].x;
        pT[nxt][skk + 1][col] = pv4[i].y;
        pT[nxt][skk + 2][col] = pv4[i].z;
        pT[nxt][skk + 3][col] = pv4[i].w;
        *(float4*)&cL[nxt][row][skk] = cv4[i];
      }
    }
    __syncthreads();
  }

  // epilogue: per-lane first-min over its 4 clusters, then exact first-min
  // across the 16 quads sharing each point via (value,index) shuffle reduce.
  float c2v[4];
#pragma unroll
  for (int j = 0; j < 4; ++j) c2v[j] = c2g[r * L_ + l0 + j];

#pragma unroll
  for (int i = 0; i < 4; ++i) {
    const int n = n0 + p0 + i;
    const float x2i = x2g[r * N_ + n];
    float bv = 3.4e38f;
    int bi = 0;
#pragma unroll
    for (int j = 0; j < 4; ++j) {
      float d2 = (x2i + c2v[j]) - 2.0f * acc[i][j];
      if (d2 < bv) { bv = d2; bi = l0 + j; }
    }
#pragma unroll
    for (int m = 4; m <= 32; m <<= 1) {
      float ov = __shfl_xor(bv, m);
      int oi = __shfl_xor(bi, m);
      if (ov < bv || (ov == bv && oi < bi)) { bv = ov; bi = oi; }
    }
    if (qq == 0) {
      labels[r * N_ + n] = bi;
      atomicAdd(&hist[bi], 1);             // block-local histogram (deterministic)
    }
  }
  __syncthreads();
  if (t < L_) atomicAdd(&counts[r * L_ + t], hist[t]);   // integer: bit-exact
}

// ---------------------------------------------------------------------------
// Partial per-cluster sums. Block = (dchunk 0..7, seg, r): 128 dims, 512 pts.
// 32 KB LDS -> 4 blocks/CU. 8-deep load pipeline; adds strictly n-ascending
// per (l,dim) -> bit-identical summation order; psums layout unchanged.
// ---------------------------------------------------------------------------
__global__ __launch_bounds__(128, 2) void k_update(const float* __restrict__ pts,
                                                   const int* __restrict__ labels,
                                                   float* __restrict__ psums) {
  __shared__ float acc[L_ * 128];
  __shared__ int lab[512];
  const int dch = blockIdx.x;   // 0..7
  const int seg = blockIdx.y;   // 0..7
  const int r   = blockIdx.z;   // 0..7
  const int t = threadIdx.x;    // 0..127

  for (int i = t; i < L_ * 128; i += 128) acc[i] = 0.f;
  for (int i = t; i < 512; i += 128) lab[i] = labels[r * N_ + seg * 512 + i];
  __syncthreads();

  const float* P = pts + ((size_t)r * N_ + seg * 512) * D_ + dch * 128 + t;
  float vbuf[8];
#pragma unroll
  for (int w = 0; w < 8; ++w) vbuf[w] = P[(size_t)w * D_];
  for (int nb = 0; nb < 504; nb += 8) {
#pragma unroll
    for (int w = 0; w < 8; ++w) {
      const int n = nb + w;
      const float cur = vbuf[w];
      vbuf[w] = P[(size_t)(n + 8) * D_];        // prefetch 8 ahead
      acc[lab[n] * 128 + t] += cur;             // in-order adds (bit-exact)
    }
  }
#pragma unroll
  for (int w = 0; w < 8; ++w) acc[lab[504 + w] * 128 + t] += vbuf[w];
  __syncthreads();

  float* S = psums + (((size_t)r * SEGS + seg) * L_) * D_ + dch * 128;
  for (int i = t; i < L_ * 128; i += 128) {
    int l = i >> 7, dd = i & 127;
    S[(size_t)l * D_ + dd] = acc[i];
  }
}

// ---------------------------------------------------------------------------
// Reduce partial sums -> new centers + c2. One block per (r,l).
// Re-zeroes counts for the next iteration's k_assign histogram.
// ---------------------------------------------------------------------------
__global__ __launch_bounds__(256) void k_reduce(const float* __restrict__ psums,
                                                int* __restrict__ counts,
                                                float* __restrict__ centers,
                                                float* __restrict__ c2) {
  const int l = blockIdx.x, r = blockIdx.y, t = threadIdx.x;
  const int cnt = counts[r * L_ + l];
  const float denom = fmaxf((float)cnt, 1.0f);

  float4 s = {0.f, 0.f, 0.f, 0.f};
#pragma unroll
  for (int seg = 0; seg < SEGS; ++seg) {
    const float4 v = *(const float4*)(psums + (((size_t)r * SEGS + seg) * L_ + l) * D_ + t * 4);
    s.x += v.x; s.y += v.y; s.z += v.z; s.w += v.w;
  }
  float4* Crow = (float4*)(centers + ((size_t)r * L_ + l) * D_);
  float4 cn;
  if (cnt > 0) {
    cn.x = s.x / denom; cn.y = s.y / denom; cn.z = s.z / denom; cn.w = s.w / denom;
  } else {
    cn = Crow[t];
  }
  Crow[t] = cn;

  float ssq = cn.x * cn.x + cn.y * cn.y + cn.z * cn.z + cn.w * cn.w;
  __shared__ float red[4];
  const int lane = t & 63, wave = t >> 6;
#pragma unroll
  for (int m = 32; m > 0; m >>= 1) ssq += __shfl_down(ssq, m);
  if (lane == 0) red[wave] = ssq;
  __syncthreads();
  if (t == 0) {
    c2[r * L_ + l] = red[0] + red[1] + red[2] + red[3];
    counts[r * L_ + l] = 0;   // all threads read cnt before this barrier
  }
}

// ---------------------------------------------------------------------------
// Final gather: out[row] = centers[r][labels[row]] — 4 rows per block.
// ---------------------------------------------------------------------------
__global__ __launch_bounds__(256) void k_final(const float* __restrict__ centers,
                                               const int* __restrict__ labels,
                                               float* __restrict__ out) {
  const int t = threadIdx.x;
  const int row = blockIdx.x * 4 + (t >> 6);
  const int lane = t & 63;
  const int r = row >> 12;
  const int lab = labels[row];
  const float4* src = (const float4*)(centers + ((size_t)r * L_ + lab) * D_);
  float4* dst = (float4*)(out + (size_t)row * D_);
#pragma unroll
  for (int i = 0; i < 4; ++i) dst[lane + 64 * i] = src[lane + 64 * i];
}

// ---------------------------------------------------------------------------
extern "C" void kernel_launch(void* const* d_in, const int* in_sizes, int n_in,
                              void* d_out, int out_size, void* d_ws, size_t ws_size,
                              hipStream_t stream) {
  const float* x = (const float*)d_in[0];   // [512, 65536] == pts [8][4096][1024]
  float* out = (float*)d_out;               // [512, 65536] float32
  char* ws = (char*)d_ws;

  // workspace layout (bytes)
  float* centers = (float*)(ws + 0);                        // 2 MB
  float* c2      = (float*)(ws + 2097152);                  // 2 KB
  float* x2      = (float*)(ws + 2099200);                  // 128 KB
  int*   labels  = (int*)  (ws + 2230272);                  // 128 KB
  int*   counts  = (int*)  (ws + 2361344);                  // 2 KB
  int*   initidx = (int*)  (ws + 2363392);                  // 2 KB
  float* psums   = (float*)(ws + 2365440);                  // 16 MB
  (void)in_sizes; (void)n_in; (void)out_size; (void)ws_size;

  // fused rng (8 blocks) + x2 (2048 blocks)
  k_rng_x2<<<dim3(R_ + ROWS / 16), 1024, 0, stream>>>(x, x2, initidx);
  k_gather_init<<<dim3(L_, R_), 256, 0, stream>>>(x, initidx, centers, c2, counts);

  for (int it = 0; it < ITERS; ++it) {
    k_assign<<<dim3(N_ / BN, R_), 256, 0, stream>>>(x, centers, c2, x2, labels, counts);
    k_update<<<dim3(8, SEGS, R_), 128, 0, stream>>>(x, labels, psums);
    k_reduce<<<dim3(L_, R_), 256, 0, stream>>>(psums, counts, centers, c2);
  }
  k_assign<<<dim3(N_ / BN, R_), 256, 0, stream>>>(x, centers, c2, x2, labels, counts);
  k_final<<<dim3(ROWS / 4), 256, 0, stream>>>(centers, labels, out);
}